// Round 8
// baseline (344.070 us; speedup 1.0000x reference)
//
#include <hip/hip_runtime.h>
#include <cstdint>

#define NN 100000
#define NE 1600000
#define DD 128
#define NB 250            // node buckets
#define BSZ 400           // nodes per bucket  (NB*BSZ == NN)
#define NHB ((NE + 8191) / 8192)   // bucket_hist blocks = 196 (divisible by 4)

typedef unsigned int uint;
typedef unsigned short ushort;
typedef unsigned long long u64;

typedef __attribute__((ext_vector_type(8))) short short8;   // 8 bf16 (4 VGPRs)
typedef __attribute__((ext_vector_type(4))) float floatx4;  // MFMA acc

// fp32 -> bf16 bits, round-to-nearest-even
__device__ inline uint f2bf(float f) {
    uint u = __float_as_uint(f);
    return (u + 0x7fffu + ((u >> 16) & 1u)) >> 16;
}

// ---------------- Pass 1: bucket histogram partials + W prep (fused) ----------------
// bcp layout: TRANSPOSED, bcp[bucket][block] -> contiguous uint4 reduce in pass 2.
// prep_w folded in: first 16384 threads also emit bf16-transposed W1/W2.
__global__ __launch_bounds__(256) void bucket_hist(const int* __restrict__ dst,
                                                   uint* __restrict__ bcp,
                                                   const float* __restrict__ W1,
                                                   const float* __restrict__ W2,
                                                   ushort* __restrict__ Wt1,
                                                   ushort* __restrict__ Wt2) {
    __shared__ uint h[NB];
    int tid = threadIdx.x;
    int gi = blockIdx.x * 256 + tid;
    if (gi < DD * DD) {                       // one-shot weight transpose+convert
        int k = gi >> 7, n = gi & 127;        // W[k][n] row-major
        Wt1[n * DD + k] = (ushort)f2bf(W1[gi]);
        Wt2[n * DD + k] = (ushort)f2bf(W2[gi]);
    }
    if (tid < NB) h[tid] = 0u;
    __syncthreads();
    int e0 = blockIdx.x * 8192 + tid;
#pragma unroll
    for (int k = 0; k < 32; ++k) {
        int e = e0 + 256 * k;
        if (e < NE) atomicAdd(&h[(uint)dst[e] / BSZ], 1u);
    }
    __syncthreads();
    if (tid < NB) bcp[(size_t)tid * NHB + blockIdx.x] = h[tid];
}

// ---------------- Pass 2: reduce partials + exclusive bucket prefix ----------------
// [R7 lesson: do NOT fuse this into bucket_append via a device-memory flag —
//  rocprof dispatch replay can re-run append with a stale flag -> bcur race ->
//  OOB writes. Keep the launch idempotent.]
__global__ __launch_bounds__(256) void bucket_prefix(const uint* __restrict__ bcp,
                                                     uint* __restrict__ bbase,
                                                     uint* __restrict__ bcur) {
    __shared__ uint cnt[NB];
    int tid = threadIdx.x;
    if (tid < NB) {
        const uint4* p = (const uint4*)(bcp + (size_t)tid * NHB);
        uint s = 0;
#pragma unroll 7
        for (int j = 0; j < NHB / 4; ++j) {     // 49 vec4 loads, contiguous
            uint4 v = p[j];
            s += v.x + v.y + v.z + v.w;
        }
        cnt[tid] = s;
    }
    __syncthreads();
    int lane = tid;
    if (lane < 64) {
        uint v[4], s = 0;
#pragma unroll
        for (int k = 0; k < 4; ++k) {
            int i = lane * 4 + k;
            v[k] = (i < NB) ? cnt[i] : 0u;
            s += v[k];
        }
        uint inc = s;
#pragma unroll
        for (int d = 1; d < 64; d <<= 1) {
            uint t = __shfl_up(inc, (unsigned)d, 64);
            if (lane >= d) inc += t;
        }
        uint run = inc - s;      // exclusive chunk base
#pragma unroll
        for (int k = 0; k < 4; ++k) {
            int i = lane * 4 + k;
            if (i < NB) { bbase[i] = run; bcur[i] = run; run += v[k]; }
        }
        if (lane == 63) bbase[NB] = run;   // == NE
    }
}

// ---------------- Pass 3: block-aggregated append into bucket regions ----------------
// payload: {src, (dstLocal<<23) | wq23}
__global__ __launch_bounds__(256) void bucket_append(const int* __restrict__ src,
                                                     const int* __restrict__ dst,
                                                     const float* __restrict__ w,
                                                     uint* __restrict__ bcur,
                                                     int2* __restrict__ etmp) {
    __shared__ uint h[NB];
    __shared__ uint res[NB];
    int tid = threadIdx.x;
    if (tid < NB) h[tid] = 0u;
    __syncthreads();
    int e0 = blockIdx.x * 4096 + tid;
    uint rank[16], bkt[16];
#pragma unroll
    for (int k = 0; k < 16; ++k) {
        int e = e0 + 256 * k;
        if (e < NE) {
            uint b = (uint)dst[e] / BSZ;
            bkt[k] = b;
            rank[k] = atomicAdd(&h[b], 1u);
        } else bkt[k] = 0xffffffffu;
    }
    __syncthreads();
    if (tid < NB) res[tid] = h[tid] ? atomicAdd(&bcur[tid], h[tid]) : 0u;
    __syncthreads();
#pragma unroll
    for (int k = 0; k < 16; ++k) {
        if (bkt[k] != 0xffffffffu) {
            int e = e0 + 256 * k;
            uint dl = (uint)dst[e] - bkt[k] * BSZ;
            uint wq = (uint)(w[e] * 8388608.0f);
            if (wq > 8388607u) wq = 8388607u;
            etmp[res[bkt[k]] + rank[k]] = make_int2(src[e], (int)((dl << 23) | wq));
        }
    }
}

// ---------------- Pass 4: per-bucket deg->dis, scan -> rowstart, placement ----------------
// 1024 threads/block (16 waves/CU) — grid is ~1 block/CU, so per-block thread
// parallelism is the latency-hiding lever.
__global__ __launch_bounds__(1024) void bucket_build(const int2* __restrict__ etmp,
                                                     const uint* __restrict__ bbase,
                                                     float* __restrict__ dis,
                                                     int* __restrict__ hist_g,
                                                     int* __restrict__ rowstart,
                                                     int2* __restrict__ edges) {
    __shared__ u64   wc[BSZ];       // (count<<40) | sum(wq23)
    __shared__ uint  cur[BSZ];
    __shared__ float disl[BSZ];
    int tid = threadIdx.x;
    int b = blockIdx.x;
    int n0 = b * BSZ;
    for (int i = tid; i < BSZ; i += 1024) wc[i] = 0ull;
    __syncthreads();
    uint base = bbase[b], end = bbase[b + 1];
    for (uint i = base + tid; i < end; i += 1024) {
        uint y = (uint)etmp[i].y;
        uint dl = y >> 23;
        atomicAdd(&wc[dl], ((u64)1 << 40) | (u64)(y & 0x7fffffu));
    }
    __syncthreads();
    // exclusive scan of counts in wave 0 (chunk of 7 per lane; 7*64=448>=400)
    if (tid < 64) {
        uint v[7], s = 0;
#pragma unroll
        for (int k = 0; k < 7; ++k) {
            int i = tid * 7 + k;
            v[k] = (i < BSZ) ? (uint)(wc[i] >> 40) : 0u;
            s += v[k];
        }
        uint inc = s;
#pragma unroll
        for (int d = 1; d < 64; d <<= 1) {
            uint t = __shfl_up(inc, (unsigned)d, 64);
            if (tid >= d) inc += t;
        }
        uint run = inc - s;
#pragma unroll
        for (int k = 0; k < 7; ++k) {
            int i = tid * 7 + k;
            if (i < BSZ) { cur[i] = run; run += v[k]; }
        }
    }
    __syncthreads();
    // per-node outputs (rowstart snapshot BEFORE placement mutates cur)
    for (int i = tid; i < BSZ; i += 1024) {
        u64 v = wc[i];
        float wsum = (float)(v & 0xffffffffffull) * (1.0f / 8388608.0f);
        float ds = rsqrtf(1.0f + wsum);
        disl[i] = ds;
        dis[n0 + i] = ds;
        hist_g[n0 + i] = (int)(v >> 40);
        rowstart[n0 + i] = (int)(base + cur[i]);
    }
    __syncthreads();
    // placement into block-exclusive region [base, end)
    for (uint i = base + tid; i < end; i += 1024) {
        int2 e = etmp[i];
        uint y = (uint)e.y;
        uint dl = y >> 23;
        float wv = (float)(y & 0x7fffffu) * (1.0f / 8388608.0f);
        uint p = atomicAdd(&cur[dl], 1u);
        float nrm = wv * disl[dl];
        edges[base + p] = make_int2(e.x, __float_as_int(nrm));
    }
}

// ---------------- MFMA GEMM: HB[r,:] = bf16( (X[r,:] @ W) * dis[r] ) ----------------
// W pre-converted/transposed (bf16 [n][k]); staging is a pure vectorized short8
// copy into padded LDS (WTS=136 -> 16B-aligned ds_read_b128, <=2-way bank
// aliasing = free). Layouts (m89/m91): A: m=lane&15, k=(lane>>4)*8+j;
// B: n=lane&15, same k; D: col=lane&15, row=(lane>>4)*4+reg.
#define WTS 136
#define NTILES ((NN + 63) / 64)

template <bool AF32>
__global__ __launch_bounds__(256) void gemm_mfma(const void* __restrict__ Xv,
                                                 const ushort* __restrict__ Wtg,
                                                 const float* __restrict__ dis,
                                                 ushort* __restrict__ HB) {
    __shared__ ushort Wt[DD * WTS];        // 34 KB
    int tid = threadIdx.x;
    // 128 rows x 16 chunks of 8 ushorts = 2048 units; 8 per thread
#pragma unroll
    for (int u = 0; u < 8; ++u) {
        int unit = tid + u * 256;
        int n = unit >> 4, c = unit & 15;
        short8 v = *(const short8*)(Wtg + n * DD + c * 8);
        *(short8*)&Wt[n * WTS + c * 8] = v;
    }
    __syncthreads();

    int wave = tid >> 6, lane = tid & 63;
    int q = lane >> 4, l16 = lane & 15;

    for (int tile = blockIdx.x; tile < NTILES; tile += gridDim.x) {
        int row0 = tile * 64 + wave * 16;

        int arow = row0 + l16;
        if (arow >= NN) arow = NN - 1;
        short8 afr[4];
        if (AF32) {
            const float* xr = (const float*)Xv + (size_t)arow * DD + q * 8;
#pragma unroll
            for (int ks = 0; ks < 4; ++ks) {
                float4 f0 = *(const float4*)(xr + ks * 32);
                float4 f1 = *(const float4*)(xr + ks * 32 + 4);
                uint4 u;
                u.x = f2bf(f0.x) | (f2bf(f0.y) << 16);
                u.y = f2bf(f0.z) | (f2bf(f0.w) << 16);
                u.z = f2bf(f1.x) | (f2bf(f1.y) << 16);
                u.w = f2bf(f1.z) | (f2bf(f1.w) << 16);
                afr[ks] = __builtin_bit_cast(short8, u);
            }
        } else {
            const ushort* xr = (const ushort*)Xv + (size_t)arow * DD + q * 8;
#pragma unroll
            for (int ks = 0; ks < 4; ++ks)
                afr[ks] = *(const short8*)(xr + ks * 32);
        }

        floatx4 acc[8];
#pragma unroll
        for (int ct = 0; ct < 8; ++ct) acc[ct] = (floatx4)(0.0f);

#pragma unroll
        for (int ct = 0; ct < 8; ++ct) {
            const ushort* wp = &Wt[(ct * 16 + l16) * WTS + q * 8];
#pragma unroll
            for (int ks = 0; ks < 4; ++ks) {
                short8 bfr = *(const short8*)(wp + ks * 32);
                acc[ct] = __builtin_amdgcn_mfma_f32_16x16x32_bf16(afr[ks], bfr, acc[ct], 0, 0, 0);
            }
        }

#pragma unroll
        for (int reg = 0; reg < 4; ++reg) {
            int r = row0 + q * 4 + reg;
            if (r < NN) {
                float ds = dis[r];
                ushort* orow = HB + (size_t)r * DD + l16;
#pragma unroll
                for (int ct = 0; ct < 8; ++ct)
                    orow[ct * 16] = (ushort)f2bf(acc[ct][reg] * ds);
            }
        }
    }
}

// ---------------- fused gather + self-loop + bias + PReLU ----------------
// Wave-per-node: 64 lanes = 128 channels (2 per lane, one uint gather / lane).
// Edge records at wave-uniform addresses, loaded NON-TEMPORAL as u64 (stream-
// once data; keeps L2 capacity for the hb table, which is the reuse set).
// Per edge: 1 addr op + 1 gather + 2 unpack + 2 fmac. Chunks of 16 keep >=16
// gathers in flight; one predicated tail chunk (dead src clamped to row 0,
// norm 0). Overread past edge-list end (<=120 B) lands in adjacent hb region.
// [Measured floor: 67-70 us across three structures (R1/R2/R3) — pinned at the
//  random-256B L2-miss service rate (~7 TB/s delivered incl. L2 hits).]
template <bool BF16OUT>
__global__ __launch_bounds__(256) void gather_finalize(const ushort* __restrict__ hb,
                                                       const int2* __restrict__ edges,
                                                       const int* __restrict__ rowstart,
                                                       const int* __restrict__ hist,
                                                       const float* __restrict__ dis,
                                                       const float* __restrict__ b,
                                                       const float* __restrict__ a,
                                                       void* __restrict__ xout) {
    int wid = __builtin_amdgcn_readfirstlane(threadIdx.x >> 6);
    int lane = threadIdx.x & 63;
    int node = blockIdx.x * 4 + wid;          // NN % 4 == 0
    uint lane4 = (uint)lane * 4u;

    int rs  = rowstart[node];                 // uniform address -> scalar load
    int cnt = hist[node];
    float ds = dis[node];
    const u64* ep = (const u64*)(edges + rs);
    const char* hbase = (const char*)hb;

    // self term (node's own pre-scaled row * dis[node])
    uint su = *(const uint*)(hbase + ((size_t)(uint)node << 8) + lane4);
    float2 acc0, acc1, acc2, acc3;
    acc0.x = __uint_as_float(su << 16) * ds;
    acc0.y = __uint_as_float(su & 0xffff0000u) * ds;
    acc1 = make_float2(0.f, 0.f);
    acc2 = make_float2(0.f, 0.f);
    acc3 = make_float2(0.f, 0.f);

    int full = cnt >> 4;                      // full chunks of 16
    int t = 0;
    for (; t < full; ++t) {
        u64 e[16];
#pragma unroll
        for (int k = 0; k < 16; ++k) e[k] = __builtin_nontemporal_load(&ep[t * 16 + k]);
#pragma unroll
        for (int k = 0; k < 16; ++k) {
            uint voff = ((uint)(e[k] & 0xffffffffu) << 8) + lane4;
            uint g = *(const uint*)(hbase + (size_t)voff);
            float nrm = __uint_as_float((uint)(e[k] >> 32));
            float2* ac = (k & 3) == 0 ? &acc0 : (k & 3) == 1 ? &acc1 : (k & 3) == 2 ? &acc2 : &acc3;
            ac->x += __uint_as_float(g << 16) * nrm;
            ac->y += __uint_as_float(g & 0xffff0000u) * nrm;
        }
    }
    int remn = cnt & 15;
    if (remn) {
        u64 e[16];
#pragma unroll
        for (int k = 0; k < 16; ++k) e[k] = __builtin_nontemporal_load(&ep[t * 16 + k]);  // overread ok
#pragma unroll
        for (int k = 0; k < 16; ++k) {
            bool live = k < remn;                              // uniform
            uint sidx = live ? (uint)(e[k] & 0xffffffffu) : 0u;
            float nrm = live ? __uint_as_float((uint)(e[k] >> 32)) : 0.0f;
            uint voff = (sidx << 8) + lane4;
            uint g = *(const uint*)(hbase + (size_t)voff);
            float2* ac = (k & 3) == 0 ? &acc0 : (k & 3) == 1 ? &acc1 : (k & 3) == 2 ? &acc2 : &acc3;
            ac->x += __uint_as_float(g << 16) * nrm;
            ac->y += __uint_as_float(g & 0xffff0000u) * nrm;
        }
    }

    float2 bb = ((const float2*)b)[lane];
    float2 aa = ((const float2*)a)[lane];
    float r0 = acc0.x + acc1.x + acc2.x + acc3.x + bb.x;
    float r1 = acc0.y + acc1.y + acc2.y + acc3.y + bb.y;
    r0 = r0 >= 0.f ? r0 : aa.x * r0;
    r1 = r1 >= 0.f ? r1 : aa.y * r1;
    if (BF16OUT) {
        ((uint*)xout)[(size_t)node * 64 + lane] = f2bf(r0) | (f2bf(r1) << 16);
    } else {
        u64 o = (u64)__float_as_uint(r0) | ((u64)__float_as_uint(r1) << 32);
        __builtin_nontemporal_store(o, &((u64*)xout)[(size_t)node * 64 + lane]);
    }
}

extern "C" void kernel_launch(void* const* d_in, const int* in_sizes, int n_in,
                              void* d_out, int out_size, void* d_ws, size_t ws_size,
                              hipStream_t stream) {
    const float* feat = (const float*)d_in[0];
    const int*   ei   = (const int*)d_in[1];     // [2, NE]
    const float* ew   = (const float*)d_in[2];
    const float* W1   = (const float*)d_in[3];
    const float* b1   = (const float*)d_in[4];
    const float* a1   = (const float*)d_in[5];
    const float* W2   = (const float*)d_in[6];
    const float* b2   = (const float*)d_in[7];
    const float* a2   = (const float*)d_in[8];
    float* out = (float*)d_out;

    const int* srcp = ei;
    const int* dstp = ei + NE;

    // workspace carve (bytes), all 16B-aligned
    char* wsb = (char*)d_ws;
    size_t off = 0;
    uint* bcp    = (uint*)(wsb + off); off += 262144;               // NB*NHB partials
    ushort* wt1  = (ushort*)(wsb + off); off += 2ull * DD * DD;     // 32 KB
    ushort* wt2  = (ushort*)(wsb + off); off += 2ull * DD * DD;     // 32 KB
    uint* bbase  = (uint*)(wsb + off); off += 4096;                 // NB+1
    uint* bcur   = (uint*)(wsb + off); off += 4096;                 // NB
    float* dis   = (float*)(wsb + off); off += 4ull * NN;           // NN
    int* hist    = (int*)(wsb + off); off += 4ull * NN;             // NN
    int* rowstart= (int*)(wsb + off); off += 4ull * NN;             // NN
    int2* etmp   = (int2*)(wsb + off); off += 8ull * NE;            // NE
    int2* edges  = (int2*)(wsb + off); off += 8ull * NE;            // NE (followed by hb: chunk overread safe)
    ushort* hb   = (ushort*)(wsb + off); off += 2ull * NN * DD;     // NN*DD bf16
    ushort* x1b  = (ushort*)(wsb + off); off += 2ull * NN * DD;     // NN*DD bf16

    // ---- CSR build (bucketed counting sort), weight prep fused into pass 1 ----
    bucket_hist<<<NHB, 256, 0, stream>>>(dstp, bcp, W1, W2, wt1, wt2);
    bucket_prefix<<<1, 256, 0, stream>>>(bcp, bbase, bcur);
    bucket_append<<<(NE + 4095) / 4096, 256, 0, stream>>>(srcp, dstp, ew, bcur, etmp);
    bucket_build<<<NB, 1024, 0, stream>>>(etmp, bbase, dis, hist, rowstart, edges);

    const int gemm_blocks = (NTILES + 1) / 2;   // 2 tiles/block
    const int gath_blocks = NN / 4;             // wave per node

    // ---- layer 1 ----
    gemm_mfma<true><<<gemm_blocks, 256, 0, stream>>>(feat, wt1, dis, hb);
    gather_finalize<true><<<gath_blocks, 256, 0, stream>>>(hb, edges, rowstart, hist, dis, b1, a1, x1b);
    // ---- layer 2 ----
    gemm_mfma<false><<<gemm_blocks, 256, 0, stream>>>(x1b, wt2, dis, hb);
    gather_finalize<false><<<gath_blocks, 256, 0, stream>>>(hb, edges, rowstart, hist, dis, b2, a2, out);
}